// Round 1
// baseline (1804.510 us; speedup 1.0000x reference)
//
#include <hip/hip_runtime.h>
#include <cstdint>
#include <cstddef>

#define N_USERS 100000
#define N_ITEMS 50000
#define DIM     64
#define IMG_D   1024
#define TXT_D   384
#define N_EDGES 2000000
#define N_COMB  (N_USERS + N_ITEMS)

// d_out layout (floats), concatenated in reference return order
#define OFF_UOUT 0
#define OFF_IOUT (N_USERS * DIM)
#define OFF_IIT  (OFF_IOUT + N_ITEMS * DIM)
#define OFF_TIT  (OFF_IIT + N_ITEMS * DIM)
#define OFF_IUS  (OFF_TIT + N_ITEMS * DIM)
#define OFF_TUS  (OFF_IUS + N_USERS * DIM)

typedef __attribute__((ext_vector_type(8))) short short8;
typedef __attribute__((ext_vector_type(4))) float float4v;
typedef __attribute__((ext_vector_type(4))) unsigned int uint4v;

__device__ __forceinline__ float wave_sum64(float v) {
#pragma unroll
  for (int off = 32; off; off >>= 1) v += __shfl_xor(v, off, 64);
  return v;
}

__device__ __forceinline__ unsigned int pack_bf16(float x, float y) {
  // round-to-nearest (ties away); inputs are well-behaved normals
  const unsigned int xu = __float_as_uint(x) + 0x8000u;
  const unsigned int yu = __float_as_uint(y) + 0x8000u;
  return (xu >> 16) | (yu & 0xffff0000u);
}

__device__ __forceinline__ float4v fma4(float w, const float4v x, float4v a) {
#pragma unroll
  for (int j = 0; j < 4; ++j) a[j] = fmaf(w, x[j], a[j]);
  return a;
}

// ---------------- CSR build ----------------
__global__ __launch_bounds__(256) void hist_kernel(const int* __restrict__ eu,
                                                   const int* __restrict__ ei,
                                                   int* __restrict__ cu, int* __restrict__ ci) {
  const int i = blockIdx.x * 256 + threadIdx.x;
  if (i < N_EDGES) {
    atomicAdd(&cu[eu[i]], 1);
    atomicAdd(&ci[ei[i]], 1);
  }
}

// block 0: users, block 1: items — runs both scans concurrently
__global__ __launch_bounds__(1024) void scan2_kernel(const int* __restrict__ cnt_u,
                                                     int* __restrict__ rs_u, int* __restrict__ cur_u,
                                                     const int* __restrict__ cnt_i,
                                                     int* __restrict__ rs_i, int* __restrict__ cur_i) {
  const int* counts;
  int *rs, *cur, n;
  if (blockIdx.x == 0) { counts = cnt_u; rs = rs_u; cur = cur_u; n = N_USERS; }
  else                 { counts = cnt_i; rs = rs_i; cur = cur_i; n = N_ITEMS; }
  __shared__ int part[1024];
  const int t = threadIdx.x;
  const int chunk = (n + 1023) >> 10;
  const int b = t * chunk;
  const int e = min(b + chunk, n);
  int s = 0;
  for (int j = b; j < e; ++j) s += counts[j];
  part[t] = s;
  __syncthreads();
  for (int off = 1; off < 1024; off <<= 1) {
    const int add = (t >= off) ? part[t - off] : 0;
    __syncthreads();
    part[t] += add;
    __syncthreads();
  }
  int run = (t == 0) ? 0 : part[t - 1];
  for (int j = b; j < e; ++j) {
    rs[j] = run;
    cur[j] = run;
    run += counts[j];
  }
  if (t == 1023) rs[n] = part[1023];
}

// interleaved CSR payload: one 8B record {col, w-bits} per edge per side
// → 2 scattered cachelines per edge instead of 4
__global__ __launch_bounds__(256) void fill_kernel(
    const int* __restrict__ eu, const int* __restrict__ ei,
    const float* __restrict__ vui, const float* __restrict__ viu,
    int* __restrict__ cur_u, int* __restrict__ cur_i,
    int2* __restrict__ cw_u, int2* __restrict__ cw_i) {
  const int i = blockIdx.x * 256 + threadIdx.x;
  if (i < N_EDGES) {
    const int u = eu[i], it = ei[i];
    const int p = atomicAdd(&cur_u[u], 1);
    int2 a;
    a.x = it;
    a.y = __float_as_int(vui[i]);
    cw_u[p] = a;
    const int q = atomicAdd(&cur_i[it], 1);
    int2 b;
    b.x = u;
    b.y = __float_as_int(viu[i]);
    cw_i[q] = b;
  }
}

// ---------------- W pre-swizzle into MFMA B-fragment layout (bf16) ----------------
// frag(K0idx,n0idx): lane L holds B[k=K0idx*32+(L>>4)*8+j][n=n0idx*16+(L&15)], j=0..7
// stored contiguously: elem index = ((K0idx*4+n0idx)*64 + L)*8 + j
__global__ __launch_bounds__(256) void wswizzle_kernel(const float* __restrict__ Wimg,
                                                       const float* __restrict__ Wtxt,
                                                       unsigned short* __restrict__ WBimg,
                                                       unsigned short* __restrict__ WBtxt) {
  int t = blockIdx.x * 256 + threadIdx.x;
  const float* W;
  unsigned short* WB;
  if (t < 8192) { W = Wimg; WB = WBimg; }
  else if (t < 8192 + 3072) { t -= 8192; W = Wtxt; WB = WBtxt; }
  else return;
  const int frag = t >> 6;
  const int lane = t & 63;
  const int K0idx = frag >> 2;
  const int n0idx = frag & 3;
  const int k0 = K0idx * 32 + ((lane >> 4) << 3);
  const int c = n0idx * 16 + (lane & 15);
  unsigned short us[8];
#pragma unroll
  for (int j = 0; j < 8; ++j) {
    const unsigned int b = __float_as_uint(W[(size_t)(k0 + j) * 64 + c]) + 0x8000u;
    us[j] = (unsigned short)(b >> 16);
  }
  uint4v o;
  o.x = (unsigned int)us[0] | ((unsigned int)us[1] << 16);
  o.y = (unsigned int)us[2] | ((unsigned int)us[3] << 16);
  o.z = (unsigned int)us[4] | ((unsigned int)us[5] << 16);
  o.w = (unsigned int)us[6] | ((unsigned int)us[7] << 16);
  *reinterpret_cast<uint4v*>(WB + (size_t)t * 8) = o;
}

// ---------------- MFMA GEMM: wave = 16 rows x 64 cols, no LDS ----------------
__global__ __launch_bounds__(256) void mfma_gemm_kernel(
    const float* __restrict__ Ximg, const unsigned short* __restrict__ WBimg,
    const float* __restrict__ bimg,
    const float* __restrict__ Xtxt, const unsigned short* __restrict__ WBtxt,
    const float* __restrict__ btxt,
    float* __restrict__ feat128) {
  const int TILES_IMG = N_ITEMS / 16;  // 3125
  const int wv = threadIdx.x >> 6;
  const int lane = threadIdx.x & 63;
  int tile = blockIdx.x * 4 + wv;
  if (tile >= 2 * TILES_IMG) return;

  const float* X;
  const unsigned short* WB;
  const float* bias;
  int K, nK0, c0;
  if (tile < TILES_IMG) { X = Ximg; WB = WBimg; bias = bimg; K = IMG_D; nK0 = IMG_D / 32; c0 = 0; }
  else { tile -= TILES_IMG; X = Xtxt; WB = WBtxt; bias = btxt; K = TXT_D; nK0 = TXT_D / 32; c0 = 64; }

  const int row0 = tile * 16;
  const int m = lane & 15;
  const int koff = (lane >> 4) << 3;
  const float* __restrict__ xp = X + (size_t)(row0 + m) * K + koff;
  const short8* __restrict__ wb8 = reinterpret_cast<const short8*>(WB);

  float4v acc[4];
#pragma unroll
  for (int n0 = 0; n0 < 4; ++n0) acc[n0] = (float4v){0.f, 0.f, 0.f, 0.f};

  for (int K0 = 0; K0 < nK0; ++K0) {
    const float4 xa = *reinterpret_cast<const float4*>(xp + K0 * 32);
    const float4 xb = *reinterpret_cast<const float4*>(xp + K0 * 32 + 4);
    uint4v au;
    au.x = pack_bf16(xa.x, xa.y);
    au.y = pack_bf16(xa.z, xa.w);
    au.z = pack_bf16(xb.x, xb.y);
    au.w = pack_bf16(xb.z, xb.w);
    const short8 af = __builtin_bit_cast(short8, au);
#pragma unroll
    for (int n0 = 0; n0 < 4; ++n0) {
      const short8 bf = wb8[(size_t)(K0 * 4 + n0) * 64 + lane];
      acc[n0] = __builtin_amdgcn_mfma_f32_16x16x32_bf16(af, bf, acc[n0], 0, 0, 0);
    }
  }

  // C/D: col = lane&15, row = (lane>>4)*4 + reg
  const int crow = (lane >> 4) << 2;
  const int ccol = lane & 15;
#pragma unroll
  for (int n0 = 0; n0 < 4; ++n0) {
    const float bv = bias[n0 * 16 + ccol];
#pragma unroll
    for (int r = 0; r < 4; ++r) {
      feat128[(size_t)(row0 + crow + r) * 128 + c0 + n0 * 16 + ccol] = acc[n0][r] + bv;
    }
  }
}

// ---------------- normalization statistics ----------------
__global__ __launch_bounds__(256) void stats_kernel(const float* __restrict__ ue,
                                                    const float* __restrict__ ie,
                                                    float* __restrict__ stats) {
  const int t = threadIdx.x;
  const int lane = t & 63;
  float cs = 0.f, ss = 0.f;
  const size_t total = (size_t)N_COMB * DIM;
  const size_t ubound = (size_t)N_USERS * DIM;
  const size_t stride = (size_t)gridDim.x * blockDim.x;
  for (size_t i = (size_t)blockIdx.x * blockDim.x + t; i < total; i += stride) {
    const float v = (i < ubound) ? ue[i] : ie[i - ubound];
    cs += v;
    ss += v * v;
  }
  ss = wave_sum64(ss);
  __shared__ float lcol[4][64];
  __shared__ float lss[4];
  const int wv = t >> 6;
  lcol[wv][lane] = cs;
  if (lane == 0) lss[wv] = ss;
  __syncthreads();
  if (wv == 0) {
    const float c = lcol[0][lane] + lcol[1][lane] + lcol[2][lane] + lcol[3][lane];
    atomicAdd(&stats[lane], c);
    if (lane == 0) atomicAdd(&stats[64], lss[0] + lss[1] + lss[2] + lss[3]);
  }
}

__global__ void finalize_kernel(float* __restrict__ stats) {
  const int d = threadIdx.x;  // 64 threads
  const float ssum = stats[64];
  const float m = stats[d] / (float)N_COMB;
  const float m2sum = wave_sum64(m * m);
  const float tot = ssum - (float)N_COMB * m2sum;
  const float rnm = sqrtf(tot / (float)N_COMB + 1e-6f);
  stats[d] = m;
  if (d == 0) stats[64] = 1.f / rnm;
}

__global__ __launch_bounds__(256) void normalize_kernel(
    const float* __restrict__ ue, const float* __restrict__ ie, const float* __restrict__ stats,
    float* __restrict__ uacc, float* __restrict__ iacc, float* __restrict__ i0) {
  const int lane = threadIdx.x & 63;
  const float m = stats[lane];
  const float inv = stats[64];
  const size_t total = (size_t)N_COMB * DIM;
  const size_t ubound = (size_t)N_USERS * DIM;
  const size_t stride = (size_t)gridDim.x * blockDim.x;
  for (size_t i = (size_t)blockIdx.x * blockDim.x + threadIdx.x; i < total; i += stride) {
    if (i < ubound) {
      uacc[i] = (ue[i] - m) * inv;
    } else {
      const size_t j = i - ubound;
      const float v = (ie[j] - m) * inv;
      iacc[j] = v;
      i0[j] = v;
    }
  }
}

// ---------------- triple SPMM: {O1,O2,O3} = A @ {X1,X2,X3}; acc += O3 ----------------
// wave = 1 row; quarter q walks edges s+q, s+q+4, ...; lane = 16B float4 slice of the row.
// 4 edges in flight per wave-iteration, 4x fewer VMEM instructions than scalar gathers.
__global__ __launch_bounds__(256) void spmm_triple_kernel(
    const int* __restrict__ rs, const int2* __restrict__ cw,
    const float* __restrict__ X1, int s1, const float* __restrict__ X2, int s2,
    const float* __restrict__ X3, int s3,
    float* __restrict__ O1, float* __restrict__ O2, float* __restrict__ O3,
    float* __restrict__ acc, int nrows) {
  const int lane = threadIdx.x & 63;
  const int wv = __builtin_amdgcn_readfirstlane(threadIdx.x >> 6);
  const int r = blockIdx.x * 4 + wv;
  if (r >= nrows) return;
  const int q = lane >> 4;
  const int l = lane & 15;
  const int s = rs[r], e = rs[r + 1];
  float4v a1 = {0.f, 0.f, 0.f, 0.f};
  float4v a2 = {0.f, 0.f, 0.f, 0.f};
  float4v a3 = {0.f, 0.f, 0.f, 0.f};
  int k = s + q;
  for (; k + 4 < e; k += 8) {
    const int2 c0 = cw[k];
    const int2 c1 = cw[k + 4];
    const float w0 = __int_as_float(c0.y);
    const float w1 = __int_as_float(c1.y);
    const float4v x10 = *reinterpret_cast<const float4v*>(X1 + (size_t)c0.x * s1 + l * 4);
    const float4v x20 = *reinterpret_cast<const float4v*>(X2 + (size_t)c0.x * s2 + l * 4);
    const float4v x30 = *reinterpret_cast<const float4v*>(X3 + (size_t)c0.x * s3 + l * 4);
    const float4v x11 = *reinterpret_cast<const float4v*>(X1 + (size_t)c1.x * s1 + l * 4);
    const float4v x21 = *reinterpret_cast<const float4v*>(X2 + (size_t)c1.x * s2 + l * 4);
    const float4v x31 = *reinterpret_cast<const float4v*>(X3 + (size_t)c1.x * s3 + l * 4);
    a1 = fma4(w0, x10, a1);
    a2 = fma4(w0, x20, a2);
    a3 = fma4(w0, x30, a3);
    a1 = fma4(w1, x11, a1);
    a2 = fma4(w1, x21, a2);
    a3 = fma4(w1, x31, a3);
  }
  if (k < e) {
    const int2 c0 = cw[k];
    const float w0 = __int_as_float(c0.y);
    a1 = fma4(w0, *reinterpret_cast<const float4v*>(X1 + (size_t)c0.x * s1 + l * 4), a1);
    a2 = fma4(w0, *reinterpret_cast<const float4v*>(X2 + (size_t)c0.x * s2 + l * 4), a2);
    a3 = fma4(w0, *reinterpret_cast<const float4v*>(X3 + (size_t)c0.x * s3 + l * 4), a3);
  }
  // combine quarter partials: xor 16 then 32 sums over the 4 quarters
#pragma unroll
  for (int j = 0; j < 4; ++j) {
    a1[j] += __shfl_xor(a1[j], 16, 64);
    a1[j] += __shfl_xor(a1[j], 32, 64);
    a2[j] += __shfl_xor(a2[j], 16, 64);
    a2[j] += __shfl_xor(a2[j], 32, 64);
    a3[j] += __shfl_xor(a3[j], 16, 64);
    a3[j] += __shfl_xor(a3[j], 32, 64);
  }
  if (q == 0) {
    const size_t o = (size_t)r * 64 + l * 4;
    *reinterpret_cast<float4v*>(O1 + o) = a1;
    *reinterpret_cast<float4v*>(O2 + o) = a2;
    *reinterpret_cast<float4v*>(O3 + o) = a3;
    float4v av = *reinterpret_cast<const float4v*>(acc + o);
#pragma unroll
    for (int j = 0; j < 4; ++j) av[j] += a3[j];
    *reinterpret_cast<float4v*>(acc + o) = av;
  }
}

// ---------------- final SPMM + fused epilogue ----------------
// a = (A @ X)[r]; if(O) O[r]=a; accio[r] = (accio[r]+a)/3 + .55*l2n(P[r]) + .55*l2n(Q[r])
__global__ __launch_bounds__(256) void spmm_final_kernel(
    const int* __restrict__ rs, const int2* __restrict__ cw,
    const float* __restrict__ X, float* __restrict__ O,
    const float* __restrict__ P, const float* __restrict__ Q,
    float* __restrict__ accio, int nrows) {
  const int lane = threadIdx.x & 63;
  const int wv = __builtin_amdgcn_readfirstlane(threadIdx.x >> 6);
  const int r = blockIdx.x * 4 + wv;
  if (r >= nrows) return;
  const int q = lane >> 4;
  const int l = lane & 15;
  const int s = rs[r], e = rs[r + 1];
  float4v a = {0.f, 0.f, 0.f, 0.f};
  int k = s + q;
  for (; k + 4 < e; k += 8) {
    const int2 c0 = cw[k];
    const int2 c1 = cw[k + 4];
    const float w0 = __int_as_float(c0.y);
    const float w1 = __int_as_float(c1.y);
    const float4v x0 = *reinterpret_cast<const float4v*>(X + (size_t)c0.x * 64 + l * 4);
    const float4v x1 = *reinterpret_cast<const float4v*>(X + (size_t)c1.x * 64 + l * 4);
    a = fma4(w0, x0, a);
    a = fma4(w1, x1, a);
  }
  if (k < e) {
    const int2 c0 = cw[k];
    a = fma4(__int_as_float(c0.y),
             *reinterpret_cast<const float4v*>(X + (size_t)c0.x * 64 + l * 4), a);
  }
#pragma unroll
  for (int j = 0; j < 4; ++j) {
    a[j] += __shfl_xor(a[j], 16, 64);
    a[j] += __shfl_xor(a[j], 32, 64);
  }
  const size_t o = (size_t)r * 64 + l * 4;
  // all quarters load identical 16B slices (broadcast); reduce within each quarter
  const float4v p = *reinterpret_cast<const float4v*>(P + o);
  const float4v qv = *reinterpret_cast<const float4v*>(Q + o);
  float ps = p[0] * p[0] + p[1] * p[1] + p[2] * p[2] + p[3] * p[3];
  float qs = qv[0] * qv[0] + qv[1] * qv[1] + qv[2] * qv[2] + qv[3] * qv[3];
#pragma unroll
  for (int off = 8; off; off >>= 1) {
    ps += __shfl_xor(ps, off, 64);
    qs += __shfl_xor(qs, off, 64);
  }
  const float pn = 0.55f / fmaxf(sqrtf(ps), 1e-12f);
  const float qn = 0.55f / fmaxf(sqrtf(qs), 1e-12f);
  if (q == 0) {
    if (O) *reinterpret_cast<float4v*>(O + o) = a;
    float4v av = *reinterpret_cast<const float4v*>(accio + o);
#pragma unroll
    for (int j = 0; j < 4; ++j) {
      av[j] = (av[j] + a[j]) * (1.0f / 3.0f) + pn * p[j] + qn * qv[j];
    }
    *reinterpret_cast<float4v*>(accio + o) = av;
  }
}

extern "C" void kernel_launch(void* const* d_in, const int* in_sizes, int n_in,
                              void* d_out, int out_size, void* d_ws, size_t ws_size,
                              hipStream_t stream) {
  const float* image_feats = (const float*)d_in[0];
  const float* text_feats = (const float*)d_in[1];
  const float* user_emb = (const float*)d_in[2];
  const float* item_emb = (const float*)d_in[3];
  const float* W_img = (const float*)d_in[4];
  const float* b_img = (const float*)d_in[5];
  const float* W_txt = (const float*)d_in[6];
  const float* b_txt = (const float*)d_in[7];
  const float* val_ui = (const float*)d_in[8];
  const float* val_iu = (const float*)d_in[9];
  const int* edge_u = (const int*)d_in[10];
  const int* edge_i = (const int*)d_in[11];

  float* out = (float*)d_out;
  float* u_acc = out + OFF_UOUT;
  float* i_acc = out + OFF_IOUT;
  float* img_item = out + OFF_IIT;
  float* txt_item = out + OFF_TIT;
  float* img_user = out + OFF_IUS;
  float* txt_user = out + OFF_TUS;

  // workspace carve-up (~111 MB)
  char* wsb = (char*)d_ws;
  size_t off = 0;
  auto take = [&](size_t bytes) -> void* {
    void* p = wsb + off;
    off += (bytes + 255) & ~(size_t)255;
    return p;
  };
  float* feat128 = (float*)take((size_t)N_ITEMS * 128 * 4);  // [item][0:64]=img, [64:128]=txt
  float* i0 = (float*)take((size_t)N_ITEMS * DIM * 4);
  float* i1 = (float*)take((size_t)N_ITEMS * DIM * 4);
  float* u1 = (float*)take((size_t)N_USERS * DIM * 4);       // layer-1 users, then reused for u2
  int2* cw_u = (int2*)take((size_t)N_EDGES * 8);             // interleaved {col, w}
  int2* cw_i = (int2*)take((size_t)N_EDGES * 8);
  int* rs_u = (int*)take((N_USERS + 1) * 4);
  int* cur_u = (int*)take((N_USERS + 1) * 4);
  int* rs_i = (int*)take((N_ITEMS + 1) * 4);
  int* cur_i = (int*)take((N_ITEMS + 1) * 4);
  int* cnt_u = (int*)take((size_t)N_USERS * 4);
  int* cnt_i = (int*)take((size_t)N_ITEMS * 4);
  unsigned short* WBimg = (unsigned short*)take((size_t)8192 * 8 * 2);  // 128 KB
  unsigned short* WBtxt = (unsigned short*)take((size_t)3072 * 8 * 2);  // 48 KB
  float* stats = (float*)take(65 * 4);

  hipMemsetAsync(cnt_u, 0, (size_t)N_USERS * 4, stream);
  hipMemsetAsync(cnt_i, 0, (size_t)N_ITEMS * 4, stream);
  hipMemsetAsync(stats, 0, 65 * 4, stream);

  const int eblk = (N_EDGES + 255) / 256;
  hist_kernel<<<eblk, 256, 0, stream>>>(edge_u, edge_i, cnt_u, cnt_i);
  scan2_kernel<<<2, 1024, 0, stream>>>(cnt_u, rs_u, cur_u, cnt_i, rs_i, cur_i);
  fill_kernel<<<eblk, 256, 0, stream>>>(edge_u, edge_i, val_ui, val_iu, cur_u, cur_i,
                                        cw_u, cw_i);

  wswizzle_kernel<<<44, 256, 0, stream>>>(W_img, W_txt, WBimg, WBtxt);
  const int ntiles = 2 * (N_ITEMS / 16);  // 6250
  mfma_gemm_kernel<<<(ntiles + 3) / 4, 256, 0, stream>>>(image_feats, WBimg, b_img,
                                                         text_feats, WBtxt, b_txt, feat128);

  stats_kernel<<<2048, 256, 0, stream>>>(user_emb, item_emb, stats);
  finalize_kernel<<<1, 64, 0, stream>>>(stats);
  normalize_kernel<<<2048, 256, 0, stream>>>(user_emb, item_emb, stats, u_acc, i_acc, i0);

  // user side: img_user/txt_user/u1 in one pass; u_acc += u1
  spmm_triple_kernel<<<N_USERS / 4, 256, 0, stream>>>(
      rs_u, cw_u, feat128, 128, feat128 + 64, 128, i0, 64,
      img_user, txt_user, u1, u_acc, N_USERS);
  // item side: img_item/txt_item/i1 in one pass; i_acc += i1
  spmm_triple_kernel<<<N_ITEMS / 4, 256, 0, stream>>>(
      rs_i, cw_i, img_user, 64, txt_user, 64, u1, 64,
      img_item, txt_item, i1, i_acc, N_ITEMS);
  // u2 = A_ui @ i1 (stored into u1 buffer) + fused user epilogue
  spmm_final_kernel<<<N_USERS / 4, 256, 0, stream>>>(
      rs_u, cw_u, i1, u1, img_user, txt_user, u_acc, N_USERS);
  // i2 = A_iu @ u2 + fused item epilogue
  spmm_final_kernel<<<N_ITEMS / 4, 256, 0, stream>>>(
      rs_i, cw_i, u1, nullptr, img_item, txt_item, i_acc, N_ITEMS);
}

// Round 2
// 1546.626 us; speedup vs baseline: 1.1667x; 1.1667x over previous
//
#include <hip/hip_runtime.h>
#include <cstdint>
#include <cstddef>

#define N_USERS 100000
#define N_ITEMS 50000
#define DIM     64
#define IMG_D   1024
#define TXT_D   384
#define N_EDGES 2000000
#define N_COMB  (N_USERS + N_ITEMS)

// d_out layout (floats), concatenated in reference return order
#define OFF_UOUT 0
#define OFF_IOUT (N_USERS * DIM)
#define OFF_IIT  (OFF_IOUT + N_ITEMS * DIM)
#define OFF_TIT  (OFF_IIT + N_ITEMS * DIM)
#define OFF_IUS  (OFF_TIT + N_ITEMS * DIM)
#define OFF_TUS  (OFF_IUS + N_USERS * DIM)

typedef __attribute__((ext_vector_type(8))) short short8;
typedef __attribute__((ext_vector_type(4))) float float4v;
typedef __attribute__((ext_vector_type(4))) unsigned int uint4v;

__device__ __forceinline__ float wave_sum64(float v) {
#pragma unroll
  for (int off = 32; off; off >>= 1) v += __shfl_xor(v, off, 64);
  return v;
}

__device__ __forceinline__ unsigned int pack_bf16(float x, float y) {
  // round-to-nearest (ties away); inputs are well-behaved normals
  const unsigned int xu = __float_as_uint(x) + 0x8000u;
  const unsigned int yu = __float_as_uint(y) + 0x8000u;
  return (xu >> 16) | (yu & 0xffff0000u);
}

__device__ __forceinline__ float4v fma4(float w, const float4v x, float4v a) {
#pragma unroll
  for (int j = 0; j < 4; ++j) a[j] = fmaf(w, x[j], a[j]);
  return a;
}

// ---------------- CSR build ----------------
// hist also records each edge's rank within its row (the atomic's return value),
// so fill_kernel needs no atomics at all.
__global__ __launch_bounds__(256) void hist_kernel(const int* __restrict__ eu,
                                                   const int* __restrict__ ei,
                                                   int* __restrict__ cu, int* __restrict__ ci,
                                                   int* __restrict__ pe_u, int* __restrict__ pe_i) {
  const int i = blockIdx.x * 256 + threadIdx.x;
  if (i < N_EDGES) {
    pe_u[i] = atomicAdd(&cu[eu[i]], 1);
    pe_i[i] = atomicAdd(&ci[ei[i]], 1);
  }
}

// block 0: users, block 1: items — runs both scans concurrently
__global__ __launch_bounds__(1024) void scan2_kernel(const int* __restrict__ cnt_u,
                                                     int* __restrict__ rs_u,
                                                     const int* __restrict__ cnt_i,
                                                     int* __restrict__ rs_i) {
  const int* counts;
  int *rs, n;
  if (blockIdx.x == 0) { counts = cnt_u; rs = rs_u; n = N_USERS; }
  else                 { counts = cnt_i; rs = rs_i; n = N_ITEMS; }
  __shared__ int part[1024];
  const int t = threadIdx.x;
  const int chunk = (n + 1023) >> 10;
  const int b = t * chunk;
  const int e = min(b + chunk, n);
  int s = 0;
  for (int j = b; j < e; ++j) s += counts[j];
  part[t] = s;
  __syncthreads();
  for (int off = 1; off < 1024; off <<= 1) {
    const int add = (t >= off) ? part[t - off] : 0;
    __syncthreads();
    part[t] += add;
    __syncthreads();
  }
  int run = (t == 0) ? 0 : part[t - 1];
  for (int j = b; j < e; ++j) {
    rs[j] = run;
    run += counts[j];
  }
  if (t == 1023) rs[n] = part[1023];
}

// atomic-free fill: pos = rs[row] + rank; four independent 4B scattered stores
// (measured faster than one interleaved 8B store — more MLP, no RMW chain)
__global__ __launch_bounds__(256) void fill_kernel(
    const int* __restrict__ eu, const int* __restrict__ ei,
    const float* __restrict__ vui, const float* __restrict__ viu,
    const int* __restrict__ pe_u, const int* __restrict__ pe_i,
    const int* __restrict__ rs_u, const int* __restrict__ rs_i,
    int* __restrict__ col_u, float* __restrict__ w_u,
    int* __restrict__ col_i, float* __restrict__ w_i) {
  const int i = blockIdx.x * 256 + threadIdx.x;
  if (i < N_EDGES) {
    const int u = eu[i], it = ei[i];
    const int p = rs_u[u] + pe_u[i];
    const int q = rs_i[it] + pe_i[i];
    col_u[p] = it;
    w_u[p] = vui[i];
    col_i[q] = u;
    w_i[q] = viu[i];
  }
}

// ---------------- W pre-swizzle into MFMA B-fragment layout (bf16) ----------------
// frag(K0idx,n0idx): lane L holds B[k=K0idx*32+(L>>4)*8+j][n=n0idx*16+(L&15)], j=0..7
// stored contiguously: elem index = ((K0idx*4+n0idx)*64 + L)*8 + j
__global__ __launch_bounds__(256) void wswizzle_kernel(const float* __restrict__ Wimg,
                                                       const float* __restrict__ Wtxt,
                                                       unsigned short* __restrict__ WBimg,
                                                       unsigned short* __restrict__ WBtxt) {
  int t = blockIdx.x * 256 + threadIdx.x;
  const float* W;
  unsigned short* WB;
  if (t < 8192) { W = Wimg; WB = WBimg; }
  else if (t < 8192 + 3072) { t -= 8192; W = Wtxt; WB = WBtxt; }
  else return;
  const int frag = t >> 6;
  const int lane = t & 63;
  const int K0idx = frag >> 2;
  const int n0idx = frag & 3;
  const int k0 = K0idx * 32 + ((lane >> 4) << 3);
  const int c = n0idx * 16 + (lane & 15);
  unsigned short us[8];
#pragma unroll
  for (int j = 0; j < 8; ++j) {
    const unsigned int b = __float_as_uint(W[(size_t)(k0 + j) * 64 + c]) + 0x8000u;
    us[j] = (unsigned short)(b >> 16);
  }
  uint4v o;
  o.x = (unsigned int)us[0] | ((unsigned int)us[1] << 16);
  o.y = (unsigned int)us[2] | ((unsigned int)us[3] << 16);
  o.z = (unsigned int)us[4] | ((unsigned int)us[5] << 16);
  o.w = (unsigned int)us[6] | ((unsigned int)us[7] << 16);
  *reinterpret_cast<uint4v*>(WB + (size_t)t * 8) = o;
}

// ---------------- MFMA GEMM: wave = 16 rows x 64 cols, no LDS ----------------
__global__ __launch_bounds__(256) void mfma_gemm_kernel(
    const float* __restrict__ Ximg, const unsigned short* __restrict__ WBimg,
    const float* __restrict__ bimg,
    const float* __restrict__ Xtxt, const unsigned short* __restrict__ WBtxt,
    const float* __restrict__ btxt,
    float* __restrict__ feat128) {
  const int TILES_IMG = N_ITEMS / 16;  // 3125
  const int wv = threadIdx.x >> 6;
  const int lane = threadIdx.x & 63;
  int tile = blockIdx.x * 4 + wv;
  if (tile >= 2 * TILES_IMG) return;

  const float* X;
  const unsigned short* WB;
  const float* bias;
  int K, nK0, c0;
  if (tile < TILES_IMG) { X = Ximg; WB = WBimg; bias = bimg; K = IMG_D; nK0 = IMG_D / 32; c0 = 0; }
  else { tile -= TILES_IMG; X = Xtxt; WB = WBtxt; bias = btxt; K = TXT_D; nK0 = TXT_D / 32; c0 = 64; }

  const int row0 = tile * 16;
  const int m = lane & 15;
  const int koff = (lane >> 4) << 3;
  const float* __restrict__ xp = X + (size_t)(row0 + m) * K + koff;
  const short8* __restrict__ wb8 = reinterpret_cast<const short8*>(WB);

  float4v acc[4];
#pragma unroll
  for (int n0 = 0; n0 < 4; ++n0) acc[n0] = (float4v){0.f, 0.f, 0.f, 0.f};

  for (int K0 = 0; K0 < nK0; ++K0) {
    const float4 xa = *reinterpret_cast<const float4*>(xp + K0 * 32);
    const float4 xb = *reinterpret_cast<const float4*>(xp + K0 * 32 + 4);
    uint4v au;
    au.x = pack_bf16(xa.x, xa.y);
    au.y = pack_bf16(xa.z, xa.w);
    au.z = pack_bf16(xb.x, xb.y);
    au.w = pack_bf16(xb.z, xb.w);
    const short8 af = __builtin_bit_cast(short8, au);
#pragma unroll
    for (int n0 = 0; n0 < 4; ++n0) {
      const short8 bf = wb8[(size_t)(K0 * 4 + n0) * 64 + lane];
      acc[n0] = __builtin_amdgcn_mfma_f32_16x16x32_bf16(af, bf, acc[n0], 0, 0, 0);
    }
  }

  // C/D: col = lane&15, row = (lane>>4)*4 + reg
  const int crow = (lane >> 4) << 2;
  const int ccol = lane & 15;
#pragma unroll
  for (int n0 = 0; n0 < 4; ++n0) {
    const float bv = bias[n0 * 16 + ccol];
#pragma unroll
    for (int r = 0; r < 4; ++r) {
      feat128[(size_t)(row0 + crow + r) * 128 + c0 + n0 * 16 + ccol] = acc[n0][r] + bv;
    }
  }
}

// ---------------- normalization statistics ----------------
__global__ __launch_bounds__(256) void stats_kernel(const float* __restrict__ ue,
                                                    const float* __restrict__ ie,
                                                    float* __restrict__ stats) {
  const int t = threadIdx.x;
  const int lane = t & 63;
  float cs = 0.f, ss = 0.f;
  const size_t total = (size_t)N_COMB * DIM;
  const size_t ubound = (size_t)N_USERS * DIM;
  const size_t stride = (size_t)gridDim.x * blockDim.x;
  for (size_t i = (size_t)blockIdx.x * blockDim.x + t; i < total; i += stride) {
    const float v = (i < ubound) ? ue[i] : ie[i - ubound];
    cs += v;
    ss += v * v;
  }
  ss = wave_sum64(ss);
  __shared__ float lcol[4][64];
  __shared__ float lss[4];
  const int wv = t >> 6;
  lcol[wv][lane] = cs;
  if (lane == 0) lss[wv] = ss;
  __syncthreads();
  if (wv == 0) {
    const float c = lcol[0][lane] + lcol[1][lane] + lcol[2][lane] + lcol[3][lane];
    atomicAdd(&stats[lane], c);
    if (lane == 0) atomicAdd(&stats[64], lss[0] + lss[1] + lss[2] + lss[3]);
  }
}

__global__ void finalize_kernel(float* __restrict__ stats) {
  const int d = threadIdx.x;  // 64 threads
  const float ssum = stats[64];
  const float m = stats[d] / (float)N_COMB;
  const float m2sum = wave_sum64(m * m);
  const float tot = ssum - (float)N_COMB * m2sum;
  const float rnm = sqrtf(tot / (float)N_COMB + 1e-6f);
  stats[d] = m;
  if (d == 0) stats[64] = 1.f / rnm;
}

__global__ __launch_bounds__(256) void normalize_kernel(
    const float* __restrict__ ue, const float* __restrict__ ie, const float* __restrict__ stats,
    float* __restrict__ uacc, float* __restrict__ iacc, float* __restrict__ i0) {
  const int lane = threadIdx.x & 63;
  const float m = stats[lane];
  const float inv = stats[64];
  const size_t total = (size_t)N_COMB * DIM;
  const size_t ubound = (size_t)N_USERS * DIM;
  const size_t stride = (size_t)gridDim.x * blockDim.x;
  for (size_t i = (size_t)blockIdx.x * blockDim.x + threadIdx.x; i < total; i += stride) {
    if (i < ubound) {
      uacc[i] = (ue[i] - m) * inv;
    } else {
      const size_t j = i - ubound;
      const float v = (ie[j] - m) * inv;
      iacc[j] = v;
      i0[j] = v;
    }
  }
}

// ---------------- triple SPMM: {O1,O2,O3} = A @ {X1,X2,X3}; acc += O3 ----------------
// wave = 1 row; quarter q walks edges s+q, s+q+4, ...; lane = 16B float4 slice of the row.
__global__ __launch_bounds__(256) void spmm_triple_kernel(
    const int* __restrict__ rs, const int* __restrict__ col, const float* __restrict__ w,
    const float* __restrict__ X1, int s1, const float* __restrict__ X2, int s2,
    const float* __restrict__ X3, int s3,
    float* __restrict__ O1, float* __restrict__ O2, float* __restrict__ O3,
    float* __restrict__ acc, int nrows) {
  const int lane = threadIdx.x & 63;
  const int wv = __builtin_amdgcn_readfirstlane(threadIdx.x >> 6);
  const int r = blockIdx.x * 4 + wv;
  if (r >= nrows) return;
  const int q = lane >> 4;
  const int l = lane & 15;
  const int s = rs[r], e = rs[r + 1];
  float4v a1 = {0.f, 0.f, 0.f, 0.f};
  float4v a2 = {0.f, 0.f, 0.f, 0.f};
  float4v a3 = {0.f, 0.f, 0.f, 0.f};
  int k = s + q;
  for (; k + 4 < e; k += 8) {
    const int c0 = col[k];
    const int c1 = col[k + 4];
    const float w0 = w[k];
    const float w1 = w[k + 4];
    const float4v x10 = *reinterpret_cast<const float4v*>(X1 + (size_t)c0 * s1 + l * 4);
    const float4v x20 = *reinterpret_cast<const float4v*>(X2 + (size_t)c0 * s2 + l * 4);
    const float4v x30 = *reinterpret_cast<const float4v*>(X3 + (size_t)c0 * s3 + l * 4);
    const float4v x11 = *reinterpret_cast<const float4v*>(X1 + (size_t)c1 * s1 + l * 4);
    const float4v x21 = *reinterpret_cast<const float4v*>(X2 + (size_t)c1 * s2 + l * 4);
    const float4v x31 = *reinterpret_cast<const float4v*>(X3 + (size_t)c1 * s3 + l * 4);
    a1 = fma4(w0, x10, a1);
    a2 = fma4(w0, x20, a2);
    a3 = fma4(w0, x30, a3);
    a1 = fma4(w1, x11, a1);
    a2 = fma4(w1, x21, a2);
    a3 = fma4(w1, x31, a3);
  }
  if (k < e) {
    const float w0 = w[k];
    const int c0 = col[k];
    a1 = fma4(w0, *reinterpret_cast<const float4v*>(X1 + (size_t)c0 * s1 + l * 4), a1);
    a2 = fma4(w0, *reinterpret_cast<const float4v*>(X2 + (size_t)c0 * s2 + l * 4), a2);
    a3 = fma4(w0, *reinterpret_cast<const float4v*>(X3 + (size_t)c0 * s3 + l * 4), a3);
  }
  // combine quarter partials: xor 16 then 32 sums over the 4 quarters
#pragma unroll
  for (int j = 0; j < 4; ++j) {
    a1[j] += __shfl_xor(a1[j], 16, 64);
    a1[j] += __shfl_xor(a1[j], 32, 64);
    a2[j] += __shfl_xor(a2[j], 16, 64);
    a2[j] += __shfl_xor(a2[j], 32, 64);
    a3[j] += __shfl_xor(a3[j], 16, 64);
    a3[j] += __shfl_xor(a3[j], 32, 64);
  }
  if (q == 0) {
    const size_t o = (size_t)r * 64 + l * 4;
    *reinterpret_cast<float4v*>(O1 + o) = a1;
    *reinterpret_cast<float4v*>(O2 + o) = a2;
    *reinterpret_cast<float4v*>(O3 + o) = a3;
    float4v av = *reinterpret_cast<const float4v*>(acc + o);
#pragma unroll
    for (int j = 0; j < 4; ++j) av[j] += a3[j];
    *reinterpret_cast<float4v*>(acc + o) = av;
  }
}

// ---------------- final SPMM + fused epilogue ----------------
// a = (A @ X)[r]; if(O) O[r]=a; accio[r] = (accio[r]+a)/3 + .55*l2n(P[r]) + .55*l2n(Q[r])
__global__ __launch_bounds__(256) void spmm_final_kernel(
    const int* __restrict__ rs, const int* __restrict__ col, const float* __restrict__ w,
    const float* __restrict__ X, float* __restrict__ O,
    const float* __restrict__ P, const float* __restrict__ Q,
    float* __restrict__ accio, int nrows) {
  const int lane = threadIdx.x & 63;
  const int wv = __builtin_amdgcn_readfirstlane(threadIdx.x >> 6);
  const int r = blockIdx.x * 4 + wv;
  if (r >= nrows) return;
  const int q = lane >> 4;
  const int l = lane & 15;
  const int s = rs[r], e = rs[r + 1];
  float4v a = {0.f, 0.f, 0.f, 0.f};
  int k = s + q;
  for (; k + 4 < e; k += 8) {
    const int c0 = col[k];
    const int c1 = col[k + 4];
    const float w0 = w[k];
    const float w1 = w[k + 4];
    const float4v x0 = *reinterpret_cast<const float4v*>(X + (size_t)c0 * 64 + l * 4);
    const float4v x1 = *reinterpret_cast<const float4v*>(X + (size_t)c1 * 64 + l * 4);
    a = fma4(w0, x0, a);
    a = fma4(w1, x1, a);
  }
  if (k < e) {
    a = fma4(w[k], *reinterpret_cast<const float4v*>(X + (size_t)col[k] * 64 + l * 4), a);
  }
#pragma unroll
  for (int j = 0; j < 4; ++j) {
    a[j] += __shfl_xor(a[j], 16, 64);
    a[j] += __shfl_xor(a[j], 32, 64);
  }
  const size_t o = (size_t)r * 64 + l * 4;
  // all quarters load identical 16B slices (broadcast); reduce within each quarter
  const float4v p = *reinterpret_cast<const float4v*>(P + o);
  const float4v qv = *reinterpret_cast<const float4v*>(Q + o);
  float ps = p[0] * p[0] + p[1] * p[1] + p[2] * p[2] + p[3] * p[3];
  float qs = qv[0] * qv[0] + qv[1] * qv[1] + qv[2] * qv[2] + qv[3] * qv[3];
#pragma unroll
  for (int off = 8; off; off >>= 1) {
    ps += __shfl_xor(ps, off, 64);
    qs += __shfl_xor(qs, off, 64);
  }
  const float pn = 0.55f / fmaxf(sqrtf(ps), 1e-12f);
  const float qn = 0.55f / fmaxf(sqrtf(qs), 1e-12f);
  if (q == 0) {
    if (O) *reinterpret_cast<float4v*>(O + o) = a;
    float4v av = *reinterpret_cast<const float4v*>(accio + o);
#pragma unroll
    for (int j = 0; j < 4; ++j) {
      av[j] = (av[j] + a[j]) * (1.0f / 3.0f) + pn * p[j] + qn * qv[j];
    }
    *reinterpret_cast<float4v*>(accio + o) = av;
  }
}

extern "C" void kernel_launch(void* const* d_in, const int* in_sizes, int n_in,
                              void* d_out, int out_size, void* d_ws, size_t ws_size,
                              hipStream_t stream) {
  const float* image_feats = (const float*)d_in[0];
  const float* text_feats = (const float*)d_in[1];
  const float* user_emb = (const float*)d_in[2];
  const float* item_emb = (const float*)d_in[3];
  const float* W_img = (const float*)d_in[4];
  const float* b_img = (const float*)d_in[5];
  const float* W_txt = (const float*)d_in[6];
  const float* b_txt = (const float*)d_in[7];
  const float* val_ui = (const float*)d_in[8];
  const float* val_iu = (const float*)d_in[9];
  const int* edge_u = (const int*)d_in[10];
  const int* edge_i = (const int*)d_in[11];

  float* out = (float*)d_out;
  float* u_acc = out + OFF_UOUT;
  float* i_acc = out + OFF_IOUT;
  float* img_item = out + OFF_IIT;
  float* txt_item = out + OFF_TIT;
  float* img_user = out + OFF_IUS;
  float* txt_user = out + OFF_TUS;

  // workspace carve-up (~111 MB)
  char* wsb = (char*)d_ws;
  size_t off = 0;
  auto take = [&](size_t bytes) -> void* {
    void* p = wsb + off;
    off += (bytes + 255) & ~(size_t)255;
    return p;
  };
  float* feat128 = (float*)take((size_t)N_ITEMS * 128 * 4);  // [item][0:64]=img, [64:128]=txt
  float* i0 = (float*)take((size_t)N_ITEMS * DIM * 4);
  float* i1 = (float*)take((size_t)N_ITEMS * DIM * 4);
  float* u1 = (float*)take((size_t)N_USERS * DIM * 4);       // layer-1 users, then reused for u2
  int* col_u = (int*)take((size_t)N_EDGES * 4);
  float* w_u = (float*)take((size_t)N_EDGES * 4);
  int* col_i = (int*)take((size_t)N_EDGES * 4);
  float* w_i = (float*)take((size_t)N_EDGES * 4);
  int* rs_u = (int*)take((N_USERS + 1) * 4);
  int* rs_i = (int*)take((N_ITEMS + 1) * 4);
  int* cnt_u = (int*)take((size_t)N_USERS * 4);
  int* cnt_i = (int*)take((size_t)N_ITEMS * 4);
  unsigned short* WBimg = (unsigned short*)take((size_t)8192 * 8 * 2);  // 128 KB
  unsigned short* WBtxt = (unsigned short*)take((size_t)3072 * 8 * 2);  // 48 KB
  float* stats = (float*)take(65 * 4);

  // per-edge ranks: used only BEFORE mfma_gemm writes feat128 — alias onto its space
  int* pe_u = (int*)feat128;            // 8 MB
  int* pe_i = pe_u + N_EDGES;           // 8 MB (feat128 is 25.6 MB total)

  hipMemsetAsync(cnt_u, 0, (size_t)N_USERS * 4, stream);
  hipMemsetAsync(cnt_i, 0, (size_t)N_ITEMS * 4, stream);
  hipMemsetAsync(stats, 0, 65 * 4, stream);

  const int eblk = (N_EDGES + 255) / 256;
  hist_kernel<<<eblk, 256, 0, stream>>>(edge_u, edge_i, cnt_u, cnt_i, pe_u, pe_i);
  scan2_kernel<<<2, 1024, 0, stream>>>(cnt_u, rs_u, cnt_i, rs_i);
  fill_kernel<<<eblk, 256, 0, stream>>>(edge_u, edge_i, val_ui, val_iu, pe_u, pe_i,
                                        rs_u, rs_i, col_u, w_u, col_i, w_i);

  wswizzle_kernel<<<44, 256, 0, stream>>>(W_img, W_txt, WBimg, WBtxt);
  const int ntiles = 2 * (N_ITEMS / 16);  // 6250
  mfma_gemm_kernel<<<(ntiles + 3) / 4, 256, 0, stream>>>(image_feats, WBimg, b_img,
                                                         text_feats, WBtxt, b_txt, feat128);

  stats_kernel<<<2048, 256, 0, stream>>>(user_emb, item_emb, stats);
  finalize_kernel<<<1, 64, 0, stream>>>(stats);
  normalize_kernel<<<2048, 256, 0, stream>>>(user_emb, item_emb, stats, u_acc, i_acc, i0);

  // user side: img_user/txt_user/u1 in one pass; u_acc += u1
  spmm_triple_kernel<<<N_USERS / 4, 256, 0, stream>>>(
      rs_u, col_u, w_u, feat128, 128, feat128 + 64, 128, i0, 64,
      img_user, txt_user, u1, u_acc, N_USERS);
  // item side: img_item/txt_item/i1 in one pass; i_acc += i1
  spmm_triple_kernel<<<N_ITEMS / 4, 256, 0, stream>>>(
      rs_i, col_i, w_i, img_user, 64, txt_user, 64, u1, 64,
      img_item, txt_item, i1, i_acc, N_ITEMS);
  // u2 = A_ui @ i1 (stored into u1 buffer) + fused user epilogue
  spmm_final_kernel<<<N_USERS / 4, 256, 0, stream>>>(
      rs_u, col_u, w_u, i1, u1, img_user, txt_user, u_acc, N_USERS);
  // i2 = A_iu @ u2 + fused item epilogue
  spmm_final_kernel<<<N_ITEMS / 4, 256, 0, stream>>>(
      rs_i, col_i, w_i, u1, nullptr, img_item, txt_item, i_acc, N_ITEMS);
}

// Round 3
// 1310.089 us; speedup vs baseline: 1.3774x; 1.1806x over previous
//
#include <hip/hip_runtime.h>
#include <cstdint>
#include <cstddef>

#define N_USERS 100000
#define N_ITEMS 50000
#define DIM     64
#define IMG_D   1024
#define TXT_D   384
#define N_EDGES 2000000
#define N_COMB  (N_USERS + N_ITEMS)

// d_out layout (floats), concatenated in reference return order
#define OFF_UOUT 0
#define OFF_IOUT (N_USERS * DIM)
#define OFF_IIT  (OFF_IOUT + N_ITEMS * DIM)
#define OFF_TIT  (OFF_IIT + N_ITEMS * DIM)
#define OFF_IUS  (OFF_TIT + N_ITEMS * DIM)
#define OFF_TUS  (OFF_IUS + N_USERS * DIM)

typedef __attribute__((ext_vector_type(8))) short short8;
typedef __attribute__((ext_vector_type(4))) float float4v;
typedef __attribute__((ext_vector_type(4))) unsigned int uint4v;
typedef __attribute__((ext_vector_type(4))) _Float16 half4v;

__device__ __forceinline__ float wave_sum64(float v) {
#pragma unroll
  for (int off = 32; off; off >>= 1) v += __shfl_xor(v, off, 64);
  return v;
}

__device__ __forceinline__ unsigned int pack_bf16(float x, float y) {
  const unsigned int xu = __float_as_uint(x) + 0x8000u;
  const unsigned int yu = __float_as_uint(y) + 0x8000u;
  return (xu >> 16) | (yu & 0xffff0000u);
}

// a += w * (float)x[0..3]
__device__ __forceinline__ float4v fma4h(float w, const half4v x, float4v a) {
#pragma unroll
  for (int j = 0; j < 4; ++j) a[j] = fmaf(w, (float)x[j], a[j]);
  return a;
}

__device__ __forceinline__ half4v to_h4(const float4v a) {
  half4v h;
#pragma unroll
  for (int j = 0; j < 4; ++j) h[j] = (_Float16)a[j];
  return h;
}

// ---------------- CSR build ----------------
// hist records each edge's rank within its row (atomic return value),
// so fill_kernel needs no atomics (measured: RMW chain in fill was the cost).
__global__ __launch_bounds__(256) void hist_kernel(const int* __restrict__ eu,
                                                   const int* __restrict__ ei,
                                                   int* __restrict__ cu, int* __restrict__ ci,
                                                   int* __restrict__ pe_u, int* __restrict__ pe_i) {
  const int i = blockIdx.x * 256 + threadIdx.x;
  if (i < N_EDGES) {
    pe_u[i] = atomicAdd(&cu[eu[i]], 1);
    pe_i[i] = atomicAdd(&ci[ei[i]], 1);
  }
}

// block 0: users, block 1: items — runs both scans concurrently
__global__ __launch_bounds__(1024) void scan2_kernel(const int* __restrict__ cnt_u,
                                                     int* __restrict__ rs_u,
                                                     const int* __restrict__ cnt_i,
                                                     int* __restrict__ rs_i) {
  const int* counts;
  int *rs, n;
  if (blockIdx.x == 0) { counts = cnt_u; rs = rs_u; n = N_USERS; }
  else                 { counts = cnt_i; rs = rs_i; n = N_ITEMS; }
  __shared__ int part[1024];
  const int t = threadIdx.x;
  const int chunk = (n + 1023) >> 10;
  const int b = t * chunk;
  const int e = min(b + chunk, n);
  int s = 0;
  for (int j = b; j < e; ++j) s += counts[j];
  part[t] = s;
  __syncthreads();
  for (int off = 1; off < 1024; off <<= 1) {
    const int add = (t >= off) ? part[t - off] : 0;
    __syncthreads();
    part[t] += add;
    __syncthreads();
  }
  int run = (t == 0) ? 0 : part[t - 1];
  for (int j = b; j < e; ++j) {
    rs[j] = run;
    run += counts[j];
  }
  if (t == 1023) rs[n] = part[1023];
}

// atomic-free fill: pos = rs[row] + rank; four independent 4B scattered stores
// (measured faster than one interleaved 8B store — more MLP, no RMW chain)
__global__ __launch_bounds__(256) void fill_kernel(
    const int* __restrict__ eu, const int* __restrict__ ei,
    const float* __restrict__ vui, const float* __restrict__ viu,
    const int* __restrict__ pe_u, const int* __restrict__ pe_i,
    const int* __restrict__ rs_u, const int* __restrict__ rs_i,
    int* __restrict__ col_u, float* __restrict__ w_u,
    int* __restrict__ col_i, float* __restrict__ w_i) {
  const int i = blockIdx.x * 256 + threadIdx.x;
  if (i < N_EDGES) {
    const int u = eu[i], it = ei[i];
    const int p = rs_u[u] + pe_u[i];
    const int q = rs_i[it] + pe_i[i];
    col_u[p] = it;
    w_u[p] = vui[i];
    col_i[q] = u;
    w_i[q] = viu[i];
  }
}

// ---------------- W pre-swizzle into MFMA B-fragment layout (bf16) ----------------
__global__ __launch_bounds__(256) void wswizzle_kernel(const float* __restrict__ Wimg,
                                                       const float* __restrict__ Wtxt,
                                                       unsigned short* __restrict__ WBimg,
                                                       unsigned short* __restrict__ WBtxt) {
  int t = blockIdx.x * 256 + threadIdx.x;
  const float* W;
  unsigned short* WB;
  if (t < 8192) { W = Wimg; WB = WBimg; }
  else if (t < 8192 + 3072) { t -= 8192; W = Wtxt; WB = WBtxt; }
  else return;
  const int frag = t >> 6;
  const int lane = t & 63;
  const int K0idx = frag >> 2;
  const int n0idx = frag & 3;
  const int k0 = K0idx * 32 + ((lane >> 4) << 3);
  const int c = n0idx * 16 + (lane & 15);
  unsigned short us[8];
#pragma unroll
  for (int j = 0; j < 8; ++j) {
    const unsigned int b = __float_as_uint(W[(size_t)(k0 + j) * 64 + c]) + 0x8000u;
    us[j] = (unsigned short)(b >> 16);
  }
  uint4v o;
  o.x = (unsigned int)us[0] | ((unsigned int)us[1] << 16);
  o.y = (unsigned int)us[2] | ((unsigned int)us[3] << 16);
  o.z = (unsigned int)us[4] | ((unsigned int)us[5] << 16);
  o.w = (unsigned int)us[6] | ((unsigned int)us[7] << 16);
  *reinterpret_cast<uint4v*>(WB + (size_t)t * 8) = o;
}

// ---------------- MFMA GEMM: wave = 16 rows x 64 cols, no LDS ----------------
// output goes straight to the fp16 packed gather table g_items[item][192]:
// cols [0:64]=img feat, [64:128]=txt feat ([128:192]=i0, written by normalize)
__global__ __launch_bounds__(256) void mfma_gemm_kernel(
    const float* __restrict__ Ximg, const unsigned short* __restrict__ WBimg,
    const float* __restrict__ bimg,
    const float* __restrict__ Xtxt, const unsigned short* __restrict__ WBtxt,
    const float* __restrict__ btxt,
    _Float16* __restrict__ g_items) {
  const int TILES_IMG = N_ITEMS / 16;  // 3125
  const int wv = threadIdx.x >> 6;
  const int lane = threadIdx.x & 63;
  int tile = blockIdx.x * 4 + wv;
  if (tile >= 2 * TILES_IMG) return;

  const float* X;
  const unsigned short* WB;
  const float* bias;
  int K, nK0, c0;
  if (tile < TILES_IMG) { X = Ximg; WB = WBimg; bias = bimg; K = IMG_D; nK0 = IMG_D / 32; c0 = 0; }
  else { tile -= TILES_IMG; X = Xtxt; WB = WBtxt; bias = btxt; K = TXT_D; nK0 = TXT_D / 32; c0 = 64; }

  const int row0 = tile * 16;
  const int m = lane & 15;
  const int koff = (lane >> 4) << 3;
  const float* __restrict__ xp = X + (size_t)(row0 + m) * K + koff;
  const short8* __restrict__ wb8 = reinterpret_cast<const short8*>(WB);

  float4v acc[4];
#pragma unroll
  for (int n0 = 0; n0 < 4; ++n0) acc[n0] = (float4v){0.f, 0.f, 0.f, 0.f};

  for (int K0 = 0; K0 < nK0; ++K0) {
    const float4 xa = *reinterpret_cast<const float4*>(xp + K0 * 32);
    const float4 xb = *reinterpret_cast<const float4*>(xp + K0 * 32 + 4);
    uint4v au;
    au.x = pack_bf16(xa.x, xa.y);
    au.y = pack_bf16(xa.z, xa.w);
    au.z = pack_bf16(xb.x, xb.y);
    au.w = pack_bf16(xb.z, xb.w);
    const short8 af = __builtin_bit_cast(short8, au);
#pragma unroll
    for (int n0 = 0; n0 < 4; ++n0) {
      const short8 bf = wb8[(size_t)(K0 * 4 + n0) * 64 + lane];
      acc[n0] = __builtin_amdgcn_mfma_f32_16x16x32_bf16(af, bf, acc[n0], 0, 0, 0);
    }
  }

  // C/D: col = lane&15, row = (lane>>4)*4 + reg
  const int crow = (lane >> 4) << 2;
  const int ccol = lane & 15;
#pragma unroll
  for (int n0 = 0; n0 < 4; ++n0) {
    const float bv = bias[n0 * 16 + ccol];
#pragma unroll
    for (int r = 0; r < 4; ++r) {
      g_items[(size_t)(row0 + crow + r) * 192 + c0 + n0 * 16 + ccol] =
          (_Float16)(acc[n0][r] + bv);
    }
  }
}

// ---------------- normalization statistics ----------------
__global__ __launch_bounds__(256) void stats_kernel(const float* __restrict__ ue,
                                                    const float* __restrict__ ie,
                                                    float* __restrict__ stats) {
  const int t = threadIdx.x;
  const int lane = t & 63;
  float cs = 0.f, ss = 0.f;
  const size_t total = (size_t)N_COMB * DIM;
  const size_t ubound = (size_t)N_USERS * DIM;
  const size_t stride = (size_t)gridDim.x * blockDim.x;
  for (size_t i = (size_t)blockIdx.x * blockDim.x + t; i < total; i += stride) {
    const float v = (i < ubound) ? ue[i] : ie[i - ubound];
    cs += v;
    ss += v * v;
  }
  ss = wave_sum64(ss);
  __shared__ float lcol[4][64];
  __shared__ float lss[4];
  const int wv = t >> 6;
  lcol[wv][lane] = cs;
  if (lane == 0) lss[wv] = ss;
  __syncthreads();
  if (wv == 0) {
    const float c = lcol[0][lane] + lcol[1][lane] + lcol[2][lane] + lcol[3][lane];
    atomicAdd(&stats[lane], c);
    if (lane == 0) atomicAdd(&stats[64], lss[0] + lss[1] + lss[2] + lss[3]);
  }
}

__global__ void finalize_kernel(float* __restrict__ stats) {
  const int d = threadIdx.x;  // 64 threads
  const float ssum = stats[64];
  const float m = stats[d] / (float)N_COMB;
  const float m2sum = wave_sum64(m * m);
  const float tot = ssum - (float)N_COMB * m2sum;
  const float rnm = sqrtf(tot / (float)N_COMB + 1e-6f);
  stats[d] = m;
  if (d == 0) stats[64] = 1.f / rnm;
}

// writes u_acc/i_acc fp32 (GNN accumulators in d_out) + i0 in fp16 to g_items[:,128:192]
__global__ __launch_bounds__(256) void normalize_kernel(
    const float* __restrict__ ue, const float* __restrict__ ie, const float* __restrict__ stats,
    float* __restrict__ uacc, float* __restrict__ iacc, _Float16* __restrict__ g_items) {
  const int lane = threadIdx.x & 63;
  const float m = stats[lane];
  const float inv = stats[64];
  const size_t total = (size_t)N_COMB * DIM;
  const size_t ubound = (size_t)N_USERS * DIM;
  const size_t stride = (size_t)gridDim.x * blockDim.x;
  for (size_t i = (size_t)blockIdx.x * blockDim.x + threadIdx.x; i < total; i += stride) {
    if (i < ubound) {
      uacc[i] = (ue[i] - m) * inv;
    } else {
      const size_t j = i - ubound;
      const float v = (ie[j] - m) * inv;
      iacc[j] = v;
      g_items[(j >> 6) * 192 + 128 + (j & 63)] = (_Float16)v;
    }
  }
}

// ---------------- triple SPMM over packed fp16 rows ----------------
// {a1,a2,a3}[r] = sum_k w[k] * G[col[k]][{0,64,128}+:64]
// writes O1,O2 fp32; acc += a3; and fp16: either all three into gout192[r][192]
// or just a3 into gout64[r][64].
__global__ __launch_bounds__(256) void spmm_triple_kernel(
    const int* __restrict__ rs, const int* __restrict__ col, const float* __restrict__ w,
    const _Float16* __restrict__ G,
    float* __restrict__ O1, float* __restrict__ O2,
    float* __restrict__ acc,
    _Float16* __restrict__ gout192, _Float16* __restrict__ gout64, int nrows) {
  const int lane = threadIdx.x & 63;
  const int wv = __builtin_amdgcn_readfirstlane(threadIdx.x >> 6);
  const int r = blockIdx.x * 4 + wv;
  if (r >= nrows) return;
  const int q = lane >> 4;
  const int l = lane & 15;
  const int s = rs[r], e = rs[r + 1];
  float4v a1 = {0.f, 0.f, 0.f, 0.f};
  float4v a2 = {0.f, 0.f, 0.f, 0.f};
  float4v a3 = {0.f, 0.f, 0.f, 0.f};
  int k = s + q;
  for (; k + 4 < e; k += 8) {
    const int c0 = col[k];
    const int c1 = col[k + 4];
    const float w0 = w[k];
    const float w1 = w[k + 4];
    const _Float16* g0 = G + (size_t)c0 * 192 + l * 4;
    const _Float16* g1 = G + (size_t)c1 * 192 + l * 4;
    const half4v x10 = *reinterpret_cast<const half4v*>(g0);
    const half4v x20 = *reinterpret_cast<const half4v*>(g0 + 64);
    const half4v x30 = *reinterpret_cast<const half4v*>(g0 + 128);
    const half4v x11 = *reinterpret_cast<const half4v*>(g1);
    const half4v x21 = *reinterpret_cast<const half4v*>(g1 + 64);
    const half4v x31 = *reinterpret_cast<const half4v*>(g1 + 128);
    a1 = fma4h(w0, x10, a1);
    a2 = fma4h(w0, x20, a2);
    a3 = fma4h(w0, x30, a3);
    a1 = fma4h(w1, x11, a1);
    a2 = fma4h(w1, x21, a2);
    a3 = fma4h(w1, x31, a3);
  }
  if (k < e) {
    const float w0 = w[k];
    const _Float16* g0 = G + (size_t)col[k] * 192 + l * 4;
    a1 = fma4h(w0, *reinterpret_cast<const half4v*>(g0), a1);
    a2 = fma4h(w0, *reinterpret_cast<const half4v*>(g0 + 64), a2);
    a3 = fma4h(w0, *reinterpret_cast<const half4v*>(g0 + 128), a3);
  }
  // combine quarter partials: xor 16 then 32 sums over the 4 quarters
#pragma unroll
  for (int j = 0; j < 4; ++j) {
    a1[j] += __shfl_xor(a1[j], 16, 64);
    a1[j] += __shfl_xor(a1[j], 32, 64);
    a2[j] += __shfl_xor(a2[j], 16, 64);
    a2[j] += __shfl_xor(a2[j], 32, 64);
    a3[j] += __shfl_xor(a3[j], 16, 64);
    a3[j] += __shfl_xor(a3[j], 32, 64);
  }
  if (q == 0) {
    const size_t o = (size_t)r * 64 + l * 4;
    *reinterpret_cast<float4v*>(O1 + o) = a1;
    *reinterpret_cast<float4v*>(O2 + o) = a2;
    float4v av = *reinterpret_cast<const float4v*>(acc + o);
#pragma unroll
    for (int j = 0; j < 4; ++j) av[j] += a3[j];
    *reinterpret_cast<float4v*>(acc + o) = av;
    if (gout192) {
      _Float16* gr = gout192 + (size_t)r * 192 + l * 4;
      *reinterpret_cast<half4v*>(gr) = to_h4(a1);
      *reinterpret_cast<half4v*>(gr + 64) = to_h4(a2);
      *reinterpret_cast<half4v*>(gr + 128) = to_h4(a3);
    } else {
      *reinterpret_cast<half4v*>(gout64 + o) = to_h4(a3);
    }
  }
}

// ---------------- final SPMM + fused epilogue ----------------
// a = (A @ X)[r]; if(GO) GO[r]=fp16(a); accio[r] = (accio[r]+a)/3 + .55*l2n(P[r]) + .55*l2n(Q[r])
__global__ __launch_bounds__(256) void spmm_final_kernel(
    const int* __restrict__ rs, const int* __restrict__ col, const float* __restrict__ w,
    const _Float16* __restrict__ X, _Float16* __restrict__ GO,
    const float* __restrict__ P, const float* __restrict__ Q,
    float* __restrict__ accio, int nrows) {
  const int lane = threadIdx.x & 63;
  const int wv = __builtin_amdgcn_readfirstlane(threadIdx.x >> 6);
  const int r = blockIdx.x * 4 + wv;
  if (r >= nrows) return;
  const int q = lane >> 4;
  const int l = lane & 15;
  const int s = rs[r], e = rs[r + 1];
  float4v a = {0.f, 0.f, 0.f, 0.f};
  int k = s + q;
  for (; k + 4 < e; k += 8) {
    const int c0 = col[k];
    const int c1 = col[k + 4];
    const float w0 = w[k];
    const float w1 = w[k + 4];
    const half4v x0 = *reinterpret_cast<const half4v*>(X + (size_t)c0 * 64 + l * 4);
    const half4v x1 = *reinterpret_cast<const half4v*>(X + (size_t)c1 * 64 + l * 4);
    a = fma4h(w0, x0, a);
    a = fma4h(w1, x1, a);
  }
  if (k < e) {
    a = fma4h(w[k], *reinterpret_cast<const half4v*>(X + (size_t)col[k] * 64 + l * 4), a);
  }
#pragma unroll
  for (int j = 0; j < 4; ++j) {
    a[j] += __shfl_xor(a[j], 16, 64);
    a[j] += __shfl_xor(a[j], 32, 64);
  }
  const size_t o = (size_t)r * 64 + l * 4;
  // all quarters load identical 16B slices (broadcast); reduce within each quarter
  const float4v p = *reinterpret_cast<const float4v*>(P + o);
  const float4v qv = *reinterpret_cast<const float4v*>(Q + o);
  float ps = p[0] * p[0] + p[1] * p[1] + p[2] * p[2] + p[3] * p[3];
  float qs = qv[0] * qv[0] + qv[1] * qv[1] + qv[2] * qv[2] + qv[3] * qv[3];
#pragma unroll
  for (int off = 8; off; off >>= 1) {
    ps += __shfl_xor(ps, off, 64);
    qs += __shfl_xor(qs, off, 64);
  }
  const float pn = 0.55f / fmaxf(sqrtf(ps), 1e-12f);
  const float qn = 0.55f / fmaxf(sqrtf(qs), 1e-12f);
  if (q == 0) {
    if (GO) *reinterpret_cast<half4v*>(GO + o) = to_h4(a);
    float4v av = *reinterpret_cast<const float4v*>(accio + o);
#pragma unroll
    for (int j = 0; j < 4; ++j) {
      av[j] = (av[j] + a[j]) * (1.0f / 3.0f) + pn * p[j] + qn * qv[j];
    }
    *reinterpret_cast<float4v*>(accio + o) = av;
  }
}

extern "C" void kernel_launch(void* const* d_in, const int* in_sizes, int n_in,
                              void* d_out, int out_size, void* d_ws, size_t ws_size,
                              hipStream_t stream) {
  const float* image_feats = (const float*)d_in[0];
  const float* text_feats = (const float*)d_in[1];
  const float* user_emb = (const float*)d_in[2];
  const float* item_emb = (const float*)d_in[3];
  const float* W_img = (const float*)d_in[4];
  const float* b_img = (const float*)d_in[5];
  const float* W_txt = (const float*)d_in[6];
  const float* b_txt = (const float*)d_in[7];
  const float* val_ui = (const float*)d_in[8];
  const float* val_iu = (const float*)d_in[9];
  const int* edge_u = (const int*)d_in[10];
  const int* edge_i = (const int*)d_in[11];

  float* out = (float*)d_out;
  float* u_acc = out + OFF_UOUT;
  float* i_acc = out + OFF_IOUT;
  float* img_item = out + OFF_IIT;
  float* txt_item = out + OFF_TIT;
  float* img_user = out + OFF_IUS;
  float* txt_user = out + OFF_TUS;

  // workspace carve-up (~110 MB)
  char* wsb = (char*)d_ws;
  size_t off = 0;
  auto take = [&](size_t bytes) -> void* {
    void* p = wsb + off;
    off += (bytes + 255) & ~(size_t)255;
    return p;
  };
  // fp16 packed gather tables
  _Float16* g_items = (_Float16*)take((size_t)N_ITEMS * 192 * 2);  // {img feat, txt feat, i0}
  _Float16* g_users = (_Float16*)take((size_t)N_USERS * 192 * 2);  // {img_user, txt_user, u1}
  _Float16* g_i1 = (_Float16*)take((size_t)N_ITEMS * 64 * 2);
  _Float16* g_u2 = (_Float16*)take((size_t)N_USERS * 64 * 2);
  int* col_u = (int*)take((size_t)N_EDGES * 4);
  float* w_u = (float*)take((size_t)N_EDGES * 4);
  int* col_i = (int*)take((size_t)N_EDGES * 4);
  float* w_i = (float*)take((size_t)N_EDGES * 4);
  int* rs_u = (int*)take((N_USERS + 1) * 4);
  int* rs_i = (int*)take((N_ITEMS + 1) * 4);
  int* cnt_u = (int*)take((size_t)N_USERS * 4);
  int* cnt_i = (int*)take((size_t)N_ITEMS * 4);
  unsigned short* WBimg = (unsigned short*)take((size_t)8192 * 8 * 2);  // 128 KB
  unsigned short* WBtxt = (unsigned short*)take((size_t)3072 * 8 * 2);  // 48 KB
  float* stats = (float*)take(65 * 4);

  // per-edge ranks: consumed by fill BEFORE the user triple writes g_users — alias
  int* pe_u = (int*)g_users;            // 8 MB
  int* pe_i = pe_u + N_EDGES;           // 8 MB (g_users is 38.4 MB)

  hipMemsetAsync(cnt_u, 0, (size_t)N_USERS * 4, stream);
  hipMemsetAsync(cnt_i, 0, (size_t)N_ITEMS * 4, stream);
  hipMemsetAsync(stats, 0, 65 * 4, stream);

  const int eblk = (N_EDGES + 255) / 256;
  hist_kernel<<<eblk, 256, 0, stream>>>(edge_u, edge_i, cnt_u, cnt_i, pe_u, pe_i);
  scan2_kernel<<<2, 1024, 0, stream>>>(cnt_u, rs_u, cnt_i, rs_i);
  fill_kernel<<<eblk, 256, 0, stream>>>(edge_u, edge_i, val_ui, val_iu, pe_u, pe_i,
                                        rs_u, rs_i, col_u, w_u, col_i, w_i);

  wswizzle_kernel<<<44, 256, 0, stream>>>(W_img, W_txt, WBimg, WBtxt);
  const int ntiles = 2 * (N_ITEMS / 16);  // 6250
  mfma_gemm_kernel<<<(ntiles + 3) / 4, 256, 0, stream>>>(image_feats, WBimg, b_img,
                                                         text_feats, WBtxt, b_txt, g_items);

  stats_kernel<<<2048, 256, 0, stream>>>(user_emb, item_emb, stats);
  finalize_kernel<<<1, 64, 0, stream>>>(stats);
  normalize_kernel<<<2048, 256, 0, stream>>>(user_emb, item_emb, stats, u_acc, i_acc, g_items);

  // user side: {img_user, txt_user, u1}; u_acc += u1; g_users packed fp16
  spmm_triple_kernel<<<N_USERS / 4, 256, 0, stream>>>(
      rs_u, col_u, w_u, g_items, img_user, txt_user, u_acc, g_users, nullptr, N_USERS);
  // item side: {img_item, txt_item, i1}; i_acc += i1; g_i1 fp16
  spmm_triple_kernel<<<N_ITEMS / 4, 256, 0, stream>>>(
      rs_i, col_i, w_i, g_users, img_item, txt_item, i_acc, nullptr, g_i1, N_ITEMS);
  // u2 = A_ui @ i1 (fp16 out) + fused user epilogue
  spmm_final_kernel<<<N_USERS / 4, 256, 0, stream>>>(
      rs_u, col_u, w_u, g_i1, g_u2, img_user, txt_user, u_acc, N_USERS);
  // i2 = A_iu @ u2 + fused item epilogue
  spmm_final_kernel<<<N_ITEMS / 4, 256, 0, stream>>>(
      rs_i, col_i, w_i, g_u2, nullptr, img_item, txt_item, i_acc, N_ITEMS);
}

// Round 4
// 1248.002 us; speedup vs baseline: 1.4459x; 1.0497x over previous
//
#include <hip/hip_runtime.h>
#include <cstdint>
#include <cstddef>

#define N_USERS 100000
#define N_ITEMS 50000
#define DIM     64
#define IMG_D   1024
#define TXT_D   384
#define N_EDGES 2000000
#define N_COMB  (N_USERS + N_ITEMS)

// d_out layout (floats), concatenated in reference return order
#define OFF_UOUT 0
#define OFF_IOUT (N_USERS * DIM)
#define OFF_IIT  (OFF_IOUT + N_ITEMS * DIM)
#define OFF_TIT  (OFF_IIT + N_ITEMS * DIM)
#define OFF_IUS  (OFF_TIT + N_ITEMS * DIM)
#define OFF_TUS  (OFF_IUS + N_USERS * DIM)

typedef __attribute__((ext_vector_type(8))) short short8;
typedef __attribute__((ext_vector_type(4))) float float4v;
typedef __attribute__((ext_vector_type(4))) unsigned int uint4v;
typedef __attribute__((ext_vector_type(4))) _Float16 half4v;

__device__ __forceinline__ float wave_sum64(float v) {
#pragma unroll
  for (int off = 32; off; off >>= 1) v += __shfl_xor(v, off, 64);
  return v;
}

__device__ __forceinline__ unsigned int pack_bf16(float x, float y) {
  const unsigned int xu = __float_as_uint(x) + 0x8000u;
  const unsigned int yu = __float_as_uint(y) + 0x8000u;
  return (xu >> 16) | (yu & 0xffff0000u);
}

// a += w * (float)x[0..3]
__device__ __forceinline__ float4v fma4h(float w, const half4v x, float4v a) {
#pragma unroll
  for (int j = 0; j < 4; ++j) a[j] = fmaf(w, (float)x[j], a[j]);
  return a;
}

__device__ __forceinline__ half4v to_h4(const float4v a) {
  half4v h;
#pragma unroll
  for (int j = 0; j < 4; ++j) h[j] = (_Float16)a[j];
  return h;
}

// packed CSR record: {col[16:0] << 15 | fp16_bits(w)[14:0]}  (w >= 0 so sign bit = 0)
__device__ __forceinline__ void dec_rec(unsigned int rec, int& c, float& w) {
  c = (int)(rec >> 15);
  w = (float)__builtin_bit_cast(_Float16, (unsigned short)(rec & 0x7FFFu));
}

__device__ __forceinline__ unsigned int enc_rec(int c, float w) {
  const unsigned short hb = __builtin_bit_cast(unsigned short, (_Float16)w);
  return ((unsigned int)c << 15) | (unsigned int)hb;
}

// ---------------- CSR build ----------------
// hist records each edge's rank within its row (atomic return value),
// so fill_kernel needs no atomics (measured: RMW chain in fill was the cost).
__global__ __launch_bounds__(256) void hist_kernel(const int* __restrict__ eu,
                                                   const int* __restrict__ ei,
                                                   int* __restrict__ cu, int* __restrict__ ci,
                                                   int* __restrict__ pe_u, int* __restrict__ pe_i) {
  const int i = blockIdx.x * 256 + threadIdx.x;
  if (i < N_EDGES) {
    pe_u[i] = atomicAdd(&cu[eu[i]], 1);
    pe_i[i] = atomicAdd(&ci[ei[i]], 1);
  }
}

// block 0: users, block 1: items — runs both scans concurrently
__global__ __launch_bounds__(1024) void scan2_kernel(const int* __restrict__ cnt_u,
                                                     int* __restrict__ rs_u,
                                                     const int* __restrict__ cnt_i,
                                                     int* __restrict__ rs_i) {
  const int* counts;
  int *rs, n;
  if (blockIdx.x == 0) { counts = cnt_u; rs = rs_u; n = N_USERS; }
  else                 { counts = cnt_i; rs = rs_i; n = N_ITEMS; }
  __shared__ int part[1024];
  const int t = threadIdx.x;
  const int chunk = (n + 1023) >> 10;
  const int b = t * chunk;
  const int e = min(b + chunk, n);
  int s = 0;
  for (int j = b; j < e; ++j) s += counts[j];
  part[t] = s;
  __syncthreads();
  for (int off = 1; off < 1024; off <<= 1) {
    const int add = (t >= off) ? part[t - off] : 0;
    __syncthreads();
    part[t] += add;
    __syncthreads();
  }
  int run = (t == 0) ? 0 : part[t - 1];
  for (int j = b; j < e; ++j) {
    rs[j] = run;
    run += counts[j];
  }
  if (t == 1023) rs[n] = part[1023];
}

// atomic-free fill: pos = rs[row] + rank; ONE scattered 4B store per edge per side
// (packed {col,fp16 w} record — halves dirty-line footprint vs col[]/w[] arrays)
__global__ __launch_bounds__(256) void fill_kernel(
    const int* __restrict__ eu, const int* __restrict__ ei,
    const float* __restrict__ vui, const float* __restrict__ viu,
    const int* __restrict__ pe_u, const int* __restrict__ pe_i,
    const int* __restrict__ rs_u, const int* __restrict__ rs_i,
    unsigned int* __restrict__ cw_u, unsigned int* __restrict__ cw_i) {
  const int i = blockIdx.x * 256 + threadIdx.x;
  if (i < N_EDGES) {
    const int u = eu[i], it = ei[i];
    const int p = rs_u[u] + pe_u[i];
    const int q = rs_i[it] + pe_i[i];
    cw_u[p] = enc_rec(it, vui[i]);
    cw_i[q] = enc_rec(u, viu[i]);
  }
}

// ---------------- W pre-swizzle into MFMA B-fragment layout (bf16) ----------------
__global__ __launch_bounds__(256) void wswizzle_kernel(const float* __restrict__ Wimg,
                                                       const float* __restrict__ Wtxt,
                                                       unsigned short* __restrict__ WBimg,
                                                       unsigned short* __restrict__ WBtxt) {
  int t = blockIdx.x * 256 + threadIdx.x;
  const float* W;
  unsigned short* WB;
  if (t < 8192) { W = Wimg; WB = WBimg; }
  else if (t < 8192 + 3072) { t -= 8192; W = Wtxt; WB = WBtxt; }
  else return;
  const int frag = t >> 6;
  const int lane = t & 63;
  const int K0idx = frag >> 2;
  const int n0idx = frag & 3;
  const int k0 = K0idx * 32 + ((lane >> 4) << 3);
  const int c = n0idx * 16 + (lane & 15);
  unsigned short us[8];
#pragma unroll
  for (int j = 0; j < 8; ++j) {
    const unsigned int b = __float_as_uint(W[(size_t)(k0 + j) * 64 + c]) + 0x8000u;
    us[j] = (unsigned short)(b >> 16);
  }
  uint4v o;
  o.x = (unsigned int)us[0] | ((unsigned int)us[1] << 16);
  o.y = (unsigned int)us[2] | ((unsigned int)us[3] << 16);
  o.z = (unsigned int)us[4] | ((unsigned int)us[5] << 16);
  o.w = (unsigned int)us[6] | ((unsigned int)us[7] << 16);
  *reinterpret_cast<uint4v*>(WB + (size_t)t * 8) = o;
}

// ---------------- MFMA GEMM: wave = 16 rows x 64 cols, no LDS ----------------
// output goes straight to the fp16 packed gather table g_items[item][192]:
// cols [0:64]=img feat, [64:128]=txt feat ([128:192]=i0, written by normalize)
__global__ __launch_bounds__(256) void mfma_gemm_kernel(
    const float* __restrict__ Ximg, const unsigned short* __restrict__ WBimg,
    const float* __restrict__ bimg,
    const float* __restrict__ Xtxt, const unsigned short* __restrict__ WBtxt,
    const float* __restrict__ btxt,
    _Float16* __restrict__ g_items) {
  const int TILES_IMG = N_ITEMS / 16;  // 3125
  const int wv = threadIdx.x >> 6;
  const int lane = threadIdx.x & 63;
  int tile = blockIdx.x * 4 + wv;
  if (tile >= 2 * TILES_IMG) return;

  const float* X;
  const unsigned short* WB;
  const float* bias;
  int K, nK0, c0;
  if (tile < TILES_IMG) { X = Ximg; WB = WBimg; bias = bimg; K = IMG_D; nK0 = IMG_D / 32; c0 = 0; }
  else { tile -= TILES_IMG; X = Xtxt; WB = WBtxt; bias = btxt; K = TXT_D; nK0 = TXT_D / 32; c0 = 64; }

  const int row0 = tile * 16;
  const int m = lane & 15;
  const int koff = (lane >> 4) << 3;
  const float* __restrict__ xp = X + (size_t)(row0 + m) * K + koff;
  const short8* __restrict__ wb8 = reinterpret_cast<const short8*>(WB);

  float4v acc[4];
#pragma unroll
  for (int n0 = 0; n0 < 4; ++n0) acc[n0] = (float4v){0.f, 0.f, 0.f, 0.f};

  for (int K0 = 0; K0 < nK0; ++K0) {
    const float4 xa = *reinterpret_cast<const float4*>(xp + K0 * 32);
    const float4 xb = *reinterpret_cast<const float4*>(xp + K0 * 32 + 4);
    uint4v au;
    au.x = pack_bf16(xa.x, xa.y);
    au.y = pack_bf16(xa.z, xa.w);
    au.z = pack_bf16(xb.x, xb.y);
    au.w = pack_bf16(xb.z, xb.w);
    const short8 af = __builtin_bit_cast(short8, au);
#pragma unroll
    for (int n0 = 0; n0 < 4; ++n0) {
      const short8 bf = wb8[(size_t)(K0 * 4 + n0) * 64 + lane];
      acc[n0] = __builtin_amdgcn_mfma_f32_16x16x32_bf16(af, bf, acc[n0], 0, 0, 0);
    }
  }

  // C/D: col = lane&15, row = (lane>>4)*4 + reg
  const int crow = (lane >> 4) << 2;
  const int ccol = lane & 15;
#pragma unroll
  for (int n0 = 0; n0 < 4; ++n0) {
    const float bv = bias[n0 * 16 + ccol];
#pragma unroll
    for (int r = 0; r < 4; ++r) {
      g_items[(size_t)(row0 + crow + r) * 192 + c0 + n0 * 16 + ccol] =
          (_Float16)(acc[n0][r] + bv);
    }
  }
}

// ---------------- normalization statistics ----------------
__global__ __launch_bounds__(256) void stats_kernel(const float* __restrict__ ue,
                                                    const float* __restrict__ ie,
                                                    float* __restrict__ stats) {
  const int t = threadIdx.x;
  const int lane = t & 63;
  float cs = 0.f, ss = 0.f;
  const size_t total = (size_t)N_COMB * DIM;
  const size_t ubound = (size_t)N_USERS * DIM;
  const size_t stride = (size_t)gridDim.x * blockDim.x;
  for (size_t i = (size_t)blockIdx.x * blockDim.x + t; i < total; i += stride) {
    const float v = (i < ubound) ? ue[i] : ie[i - ubound];
    cs += v;
    ss += v * v;
  }
  ss = wave_sum64(ss);
  __shared__ float lcol[4][64];
  __shared__ float lss[4];
  const int wv = t >> 6;
  lcol[wv][lane] = cs;
  if (lane == 0) lss[wv] = ss;
  __syncthreads();
  if (wv == 0) {
    const float c = lcol[0][lane] + lcol[1][lane] + lcol[2][lane] + lcol[3][lane];
    atomicAdd(&stats[lane], c);
    if (lane == 0) atomicAdd(&stats[64], lss[0] + lss[1] + lss[2] + lss[3]);
  }
}

__global__ void finalize_kernel(float* __restrict__ stats) {
  const int d = threadIdx.x;  // 64 threads
  const float ssum = stats[64];
  const float m = stats[d] / (float)N_COMB;
  const float m2sum = wave_sum64(m * m);
  const float tot = ssum - (float)N_COMB * m2sum;
  const float rnm = sqrtf(tot / (float)N_COMB + 1e-6f);
  stats[d] = m;
  if (d == 0) stats[64] = 1.f / rnm;
}

// writes u_acc/i_acc fp32 (GNN accumulators in d_out) + i0 in fp16 to g_items[:,128:192]
__global__ __launch_bounds__(256) void normalize_kernel(
    const float* __restrict__ ue, const float* __restrict__ ie, const float* __restrict__ stats,
    float* __restrict__ uacc, float* __restrict__ iacc, _Float16* __restrict__ g_items) {
  const int lane = threadIdx.x & 63;
  const float m = stats[lane];
  const float inv = stats[64];
  const size_t total = (size_t)N_COMB * DIM;
  const size_t ubound = (size_t)N_USERS * DIM;
  const size_t stride = (size_t)gridDim.x * blockDim.x;
  for (size_t i = (size_t)blockIdx.x * blockDim.x + threadIdx.x; i < total; i += stride) {
    if (i < ubound) {
      uacc[i] = (ue[i] - m) * inv;
    } else {
      const size_t j = i - ubound;
      const float v = (ie[j] - m) * inv;
      iacc[j] = v;
      g_items[(j >> 6) * 192 + 128 + (j & 63)] = (_Float16)v;
    }
  }
}

// ---------------- triple SPMM over packed fp16 rows ----------------
// {a1,a2,a3}[r] = sum_k w[k] * G[col[k]][{0,64,128}+:64]
// writes O1,O2 fp32; acc += a3; and fp16: either all three into gout192[r][192]
// or just a3 into gout64[r][64].
__global__ __launch_bounds__(256) void spmm_triple_kernel(
    const int* __restrict__ rs, const unsigned int* __restrict__ cw,
    const _Float16* __restrict__ G,
    float* __restrict__ O1, float* __restrict__ O2,
    float* __restrict__ acc,
    _Float16* __restrict__ gout192, _Float16* __restrict__ gout64, int nrows) {
  const int lane = threadIdx.x & 63;
  const int wv = __builtin_amdgcn_readfirstlane(threadIdx.x >> 6);
  const int r = blockIdx.x * 4 + wv;
  if (r >= nrows) return;
  const int q = lane >> 4;
  const int l = lane & 15;
  const int s = rs[r], e = rs[r + 1];
  float4v a1 = {0.f, 0.f, 0.f, 0.f};
  float4v a2 = {0.f, 0.f, 0.f, 0.f};
  float4v a3 = {0.f, 0.f, 0.f, 0.f};
  int k = s + q;
  for (; k + 4 < e; k += 8) {
    int c0, c1;
    float w0, w1;
    dec_rec(cw[k], c0, w0);
    dec_rec(cw[k + 4], c1, w1);
    const _Float16* g0 = G + (size_t)c0 * 192 + l * 4;
    const _Float16* g1 = G + (size_t)c1 * 192 + l * 4;
    const half4v x10 = *reinterpret_cast<const half4v*>(g0);
    const half4v x20 = *reinterpret_cast<const half4v*>(g0 + 64);
    const half4v x30 = *reinterpret_cast<const half4v*>(g0 + 128);
    const half4v x11 = *reinterpret_cast<const half4v*>(g1);
    const half4v x21 = *reinterpret_cast<const half4v*>(g1 + 64);
    const half4v x31 = *reinterpret_cast<const half4v*>(g1 + 128);
    a1 = fma4h(w0, x10, a1);
    a2 = fma4h(w0, x20, a2);
    a3 = fma4h(w0, x30, a3);
    a1 = fma4h(w1, x11, a1);
    a2 = fma4h(w1, x21, a2);
    a3 = fma4h(w1, x31, a3);
  }
  if (k < e) {
    int c0;
    float w0;
    dec_rec(cw[k], c0, w0);
    const _Float16* g0 = G + (size_t)c0 * 192 + l * 4;
    a1 = fma4h(w0, *reinterpret_cast<const half4v*>(g0), a1);
    a2 = fma4h(w0, *reinterpret_cast<const half4v*>(g0 + 64), a2);
    a3 = fma4h(w0, *reinterpret_cast<const half4v*>(g0 + 128), a3);
  }
  // combine quarter partials: xor 16 then 32 sums over the 4 quarters
#pragma unroll
  for (int j = 0; j < 4; ++j) {
    a1[j] += __shfl_xor(a1[j], 16, 64);
    a1[j] += __shfl_xor(a1[j], 32, 64);
    a2[j] += __shfl_xor(a2[j], 16, 64);
    a2[j] += __shfl_xor(a2[j], 32, 64);
    a3[j] += __shfl_xor(a3[j], 16, 64);
    a3[j] += __shfl_xor(a3[j], 32, 64);
  }
  if (q == 0) {
    const size_t o = (size_t)r * 64 + l * 4;
    *reinterpret_cast<float4v*>(O1 + o) = a1;
    *reinterpret_cast<float4v*>(O2 + o) = a2;
    float4v av = *reinterpret_cast<const float4v*>(acc + o);
#pragma unroll
    for (int j = 0; j < 4; ++j) av[j] += a3[j];
    *reinterpret_cast<float4v*>(acc + o) = av;
    if (gout192) {
      _Float16* gr = gout192 + (size_t)r * 192 + l * 4;
      *reinterpret_cast<half4v*>(gr) = to_h4(a1);
      *reinterpret_cast<half4v*>(gr + 64) = to_h4(a2);
      *reinterpret_cast<half4v*>(gr + 128) = to_h4(a3);
    } else {
      *reinterpret_cast<half4v*>(gout64 + o) = to_h4(a3);
    }
  }
}

// ---------------- final SPMM + fused epilogue ----------------
// a = (A @ X)[r]; if(GO) GO[r]=fp16(a); accio[r] = (accio[r]+a)/3 + .55*l2n(P[r]) + .55*l2n(Q[r])
__global__ __launch_bounds__(256) void spmm_final_kernel(
    const int* __restrict__ rs, const unsigned int* __restrict__ cw,
    const _Float16* __restrict__ X, _Float16* __restrict__ GO,
    const float* __restrict__ P, const float* __restrict__ Q,
    float* __restrict__ accio, int nrows) {
  const int lane = threadIdx.x & 63;
  const int wv = __builtin_amdgcn_readfirstlane(threadIdx.x >> 6);
  const int r = blockIdx.x * 4 + wv;
  if (r >= nrows) return;
  const int q = lane >> 4;
  const int l = lane & 15;
  const int s = rs[r], e = rs[r + 1];
  float4v a = {0.f, 0.f, 0.f, 0.f};
  int k = s + q;
  for (; k + 4 < e; k += 8) {
    int c0, c1;
    float w0, w1;
    dec_rec(cw[k], c0, w0);
    dec_rec(cw[k + 4], c1, w1);
    const half4v x0 = *reinterpret_cast<const half4v*>(X + (size_t)c0 * 64 + l * 4);
    const half4v x1 = *reinterpret_cast<const half4v*>(X + (size_t)c1 * 64 + l * 4);
    a = fma4h(w0, x0, a);
    a = fma4h(w1, x1, a);
  }
  if (k < e) {
    int c0;
    float w0;
    dec_rec(cw[k], c0, w0);
    a = fma4h(w0, *reinterpret_cast<const half4v*>(X + (size_t)c0 * 64 + l * 4), a);
  }
#pragma unroll
  for (int j = 0; j < 4; ++j) {
    a[j] += __shfl_xor(a[j], 16, 64);
    a[j] += __shfl_xor(a[j], 32, 64);
  }
  const size_t o = (size_t)r * 64 + l * 4;
  // all quarters load identical 16B slices (broadcast); reduce within each quarter
  const float4v p = *reinterpret_cast<const float4v*>(P + o);
  const float4v qv = *reinterpret_cast<const float4v*>(Q + o);
  float ps = p[0] * p[0] + p[1] * p[1] + p[2] * p[2] + p[3] * p[3];
  float qs = qv[0] * qv[0] + qv[1] * qv[1] + qv[2] * qv[2] + qv[3] * qv[3];
#pragma unroll
  for (int off = 8; off; off >>= 1) {
    ps += __shfl_xor(ps, off, 64);
    qs += __shfl_xor(qs, off, 64);
  }
  const float pn = 0.55f / fmaxf(sqrtf(ps), 1e-12f);
  const float qn = 0.55f / fmaxf(sqrtf(qs), 1e-12f);
  if (q == 0) {
    if (GO) *reinterpret_cast<half4v*>(GO + o) = to_h4(a);
    float4v av = *reinterpret_cast<const float4v*>(accio + o);
#pragma unroll
    for (int j = 0; j < 4; ++j) {
      av[j] = (av[j] + a[j]) * (1.0f / 3.0f) + pn * p[j] + qn * qv[j];
    }
    *reinterpret_cast<float4v*>(accio + o) = av;
  }
}

extern "C" void kernel_launch(void* const* d_in, const int* in_sizes, int n_in,
                              void* d_out, int out_size, void* d_ws, size_t ws_size,
                              hipStream_t stream) {
  const float* image_feats = (const float*)d_in[0];
  const float* text_feats = (const float*)d_in[1];
  const float* user_emb = (const float*)d_in[2];
  const float* item_emb = (const float*)d_in[3];
  const float* W_img = (const float*)d_in[4];
  const float* b_img = (const float*)d_in[5];
  const float* W_txt = (const float*)d_in[6];
  const float* b_txt = (const float*)d_in[7];
  const float* val_ui = (const float*)d_in[8];
  const float* val_iu = (const float*)d_in[9];
  const int* edge_u = (const int*)d_in[10];
  const int* edge_i = (const int*)d_in[11];

  float* out = (float*)d_out;
  float* u_acc = out + OFF_UOUT;
  float* i_acc = out + OFF_IOUT;
  float* img_item = out + OFF_IIT;
  float* txt_item = out + OFF_TIT;
  float* img_user = out + OFF_IUS;
  float* txt_user = out + OFF_TUS;

  // workspace carve-up (~95 MB)
  char* wsb = (char*)d_ws;
  size_t off = 0;
  auto take = [&](size_t bytes) -> void* {
    void* p = wsb + off;
    off += (bytes + 255) & ~(size_t)255;
    return p;
  };
  // fp16 packed gather tables
  _Float16* g_items = (_Float16*)take((size_t)N_ITEMS * 192 * 2);  // {img feat, txt feat, i0}
  _Float16* g_users = (_Float16*)take((size_t)N_USERS * 192 * 2);  // {img_user, txt_user, u1}
  _Float16* g_i1 = (_Float16*)take((size_t)N_ITEMS * 64 * 2);
  _Float16* g_u2 = (_Float16*)take((size_t)N_USERS * 64 * 2);
  unsigned int* cw_u = (unsigned int*)take((size_t)N_EDGES * 4);  // packed {col,fp16 w}
  unsigned int* cw_i = (unsigned int*)take((size_t)N_EDGES * 4);
  int* rs_u = (int*)take((N_USERS + 1) * 4);
  int* rs_i = (int*)take((N_ITEMS + 1) * 4);
  int* cnt_u = (int*)take((size_t)N_USERS * 4);
  int* cnt_i = (int*)take((size_t)N_ITEMS * 4);
  unsigned short* WBimg = (unsigned short*)take((size_t)8192 * 8 * 2);  // 128 KB
  unsigned short* WBtxt = (unsigned short*)take((size_t)3072 * 8 * 2);  // 48 KB
  float* stats = (float*)take(65 * 4);

  // per-edge ranks: consumed by fill BEFORE the user triple writes g_users — alias
  int* pe_u = (int*)g_users;            // 8 MB
  int* pe_i = pe_u + N_EDGES;           // 8 MB (g_users is 38.4 MB)

  hipMemsetAsync(cnt_u, 0, (size_t)N_USERS * 4, stream);
  hipMemsetAsync(cnt_i, 0, (size_t)N_ITEMS * 4, stream);
  hipMemsetAsync(stats, 0, 65 * 4, stream);

  const int eblk = (N_EDGES + 255) / 256;
  hist_kernel<<<eblk, 256, 0, stream>>>(edge_u, edge_i, cnt_u, cnt_i, pe_u, pe_i);
  scan2_kernel<<<2, 1024, 0, stream>>>(cnt_u, rs_u, cnt_i, rs_i);
  fill_kernel<<<eblk, 256, 0, stream>>>(edge_u, edge_i, val_ui, val_iu, pe_u, pe_i,
                                        rs_u, rs_i, cw_u, cw_i);

  wswizzle_kernel<<<44, 256, 0, stream>>>(W_img, W_txt, WBimg, WBtxt);
  const int ntiles = 2 * (N_ITEMS / 16);  // 6250
  mfma_gemm_kernel<<<(ntiles + 3) / 4, 256, 0, stream>>>(image_feats, WBimg, b_img,
                                                         text_feats, WBtxt, b_txt, g_items);

  stats_kernel<<<2048, 256, 0, stream>>>(user_emb, item_emb, stats);
  finalize_kernel<<<1, 64, 0, stream>>>(stats);
  normalize_kernel<<<2048, 256, 0, stream>>>(user_emb, item_emb, stats, u_acc, i_acc, g_items);

  // user side: {img_user, txt_user, u1}; u_acc += u1; g_users packed fp16
  spmm_triple_kernel<<<N_USERS / 4, 256, 0, stream>>>(
      rs_u, cw_u, g_items, img_user, txt_user, u_acc, g_users, nullptr, N_USERS);
  // item side: {img_item, txt_item, i1}; i_acc += i1; g_i1 fp16
  spmm_triple_kernel<<<N_ITEMS / 4, 256, 0, stream>>>(
      rs_i, cw_i, g_users, img_item, txt_item, i_acc, nullptr, g_i1, N_ITEMS);
  // u2 = A_ui @ i1 (fp16 out) + fused user epilogue
  spmm_final_kernel<<<N_USERS / 4, 256, 0, stream>>>(
      rs_u, cw_u, g_i1, g_u2, img_user, txt_user, u_acc, N_USERS);
  // i2 = A_iu @ u2 + fused item epilogue
  spmm_final_kernel<<<N_ITEMS / 4, 256, 0, stream>>>(
      rs_i, cw_i, g_u2, nullptr, img_item, txt_item, i_acc, N_ITEMS);
}